// Round 6
// baseline (173.751 us; speedup 1.0000x reference)
//
#include <hip/hip_runtime.h>

#define IMG 448.0f
#define GRID_F 64.0f
#define L_COORD 5.0f
#define L_NOOBJ 0.5f
#define ROUNDS 4
#define CELLS 256   // cells per round per block (== blockDim.x)

__device__ __forceinline__ float iou_box(float px, float py, float pw, float ph,
                                         float glx, float guy, float grx, float gdy,
                                         float g_area) {
    float plx = fmaxf(0.0f, px - pw * 0.5f);
    float puy = fmaxf(0.0f, py - ph * 0.5f);
    float prx = fminf(IMG - 1.0f, px + pw * 0.5f);
    float pdy = fminf(IMG - 1.0f, py + ph * 0.5f);
    float p_area = (prx - plx) * (pdy - puy);
    float cl = fmaxf(plx, glx);
    float cr = fminf(prx, grx);
    float cu = fmaxf(puy, guy);
    float cd = fminf(pdy, gdy);
    float inter = (cr - cl + 1.0f) * (cd - cu + 1.0f);
    float denom = p_area + g_area - inter;
    float iou = inter / denom;
    return ((cr < cl) || (cd < cu)) ? 0.0f : iou;
}

__device__ __forceinline__ float cell_loss(float4 b0, float4 b1, float4 b2,
                                           float4 g0, float4 g1, float4 g2,
                                           int ij) {
    float gx = (float)(ij / 7) * GRID_F;
    float gy = (float)(ij % 7) * GRID_F;

    float glx = g1.y, guy = g1.z, grx = g1.w, gdy = g2.x;
    float g_area = (grx - glx) * (gdy - guy);

    float px0 = truncf(gx + b0.x * GRID_F);
    float py0 = truncf(gy + b0.y * GRID_F);
    float pw0 = truncf(b0.z * IMG);
    float ph0 = truncf(b0.w * IMG);
    float iou0 = iou_box(px0, py0, pw0, ph0, glx, guy, grx, gdy, g_area);

    float px1 = truncf(gx + b1.y * GRID_F);
    float py1 = truncf(gy + b1.z * GRID_F);
    float pw1 = truncf(b1.w * IMG);
    float ph1 = truncf(b2.x * IMG);
    float iou1 = iou_box(px1, py1, pw1, ph1, glx, guy, grx, gdy, g_area);

    int idx = (iou1 > iou0) ? 1 : 0;       // first-max tie-break (jnp.argmax)
    float max_iou = fmaxf(iou0, iou1);

    float exist = g2.y;
    float m = ((exist != 0.0f) && (max_iou > 0.0f)) ? 1.0f : 0.0f;

    float pmx = idx ? b1.y : b0.x;
    float pmy = idx ? b1.z : b0.y;
    float pmw = idx ? b1.w : b0.z;
    float pmh = idx ? b2.x : b0.w;
    float pmc = idx ? b2.y : b1.x;

    float dx = g0.x - pmx;
    float dy = g0.y - pmy;
    float dw = sqrtf(g0.z) - sqrtf(pmw);
    float dh = sqrtf(g0.w) - sqrtf(pmh);
    float coord = L_COORD * (dx * dx + dy * dy + dw * dw + dh * dh);

    float dconf = g1.x - pmc;
    float conf_obj = dconf * dconf;

    float dc0 = g2.z - b2.z;
    float dc1 = g2.w - b2.w;
    float cls = L_NOOBJ * (dc0 * dc0 + dc1 * dc1);

    float conf_noobj = L_NOOBJ * (b1.x * b1.x + b2.y * b2.y - m * pmc * pmc);

    return m * (coord + conf_obj + cls) + conf_noobj;
}

__global__ __launch_bounds__(256) void yolo_loss_kernel(
    const float* __restrict__ bb, const float* __restrict__ gt,
    float* __restrict__ out, int ncell) {
    // SoA LDS redistribute: slot-major, padded to 257 float4s per row so the
    // scattered writes alias banks at most 2-way (free per m136).
    __shared__ float4 sb[3][CELLS + 1];
    __shared__ float4 sg[3][CELLS + 1];
    __shared__ float warp_sums[4];

    const float4* __restrict__ bb4 = reinterpret_cast<const float4*>(bb);
    const float4* __restrict__ gt4 = reinterpret_cast<const float4*>(gt);

    int t = threadIdx.x;
    long maxf = (long)ncell * 3 - 1;  // clamp (grid divides exactly; safety only)
    float val = 0.0f;

    for (int r = 0; r < ROUNDS; ++r) {
        int base_cell = (blockIdx.x * ROUNDS + r) * CELLS;
        long fbase = (long)base_cell * 3;
        long c0 = fbase + t;
        long c1 = fbase + t + 256;
        long c2 = fbase + t + 512;
        c0 = c0 > maxf ? maxf : c0;
        c1 = c1 > maxf ? maxf : c1;
        c2 = c2 > maxf ? maxf : c2;

        // Fully-coalesced 1 KB wave-loads (6 per wave), issued before the
        // barrier that closes the previous round, so HBM latency overlaps
        // the previous round's LDS reads + compute.
        float4 vb0 = bb4[c0];
        float4 vb1 = bb4[c1];
        float4 vb2 = bb4[c2];
        float4 vg0 = gt4[c0];
        float4 vg1 = gt4[c1];
        float4 vg2 = gt4[c2];

        if (r) __syncthreads();  // previous round's LDS reads must be done

        int l0 = t, l1 = t + 256, l2 = t + 512;
        sb[l0 % 3][l0 / 3] = vb0;
        sb[l1 % 3][l1 / 3] = vb1;
        sb[l2 % 3][l2 / 3] = vb2;
        sg[l0 % 3][l0 / 3] = vg0;
        sg[l1 % 3][l1 / 3] = vg1;
        sg[l2 % 3][l2 / 3] = vg2;
        __syncthreads();

        int cell = base_cell + t;
        if (cell < ncell) {
            val += cell_loss(sb[0][t], sb[1][t], sb[2][t],
                             sg[0][t], sg[1][t], sg[2][t],
                             cell % 49);
        }
    }

    // wave64 reduce
    #pragma unroll
    for (int off = 32; off > 0; off >>= 1)
        val += __shfl_down(val, off, 64);

    int lane = threadIdx.x & 63;
    int wid = threadIdx.x >> 6;
    if (lane == 0) warp_sums[wid] = val;
    __syncthreads();
    if (threadIdx.x == 0) {
        float s = warp_sums[0] + warp_sums[1] + warp_sums[2] + warp_sums[3];
        atomicAdd(out, s);
    }
}

extern "C" void kernel_launch(void* const* d_in, const int* in_sizes, int n_in,
                              void* d_out, int out_size, void* d_ws, size_t ws_size,
                              hipStream_t stream) {
    const float* bb = (const float*)d_in[0];
    const float* gt = (const float*)d_in[1];
    float* out = (float*)d_out;
    int ncell = in_sizes[0] / 12;  // N*S*S = 1,605,632 = 1568 * 1024

    hipMemsetAsync(d_out, 0, sizeof(float), stream);
    int block = CELLS;
    int grid = (ncell + block * ROUNDS - 1) / (block * ROUNDS);  // 1568
    yolo_loss_kernel<<<grid, block, 0, stream>>>(bb, gt, out, ncell);
}

// Round 7
// 172.117 us; speedup vs baseline: 1.0095x; 1.0095x over previous
//
#include <hip/hip_runtime.h>

#define IMG 448.0f
#define GRID_F 64.0f
#define L_COORD 5.0f
#define L_NOOBJ 0.5f
#define NBLOCKS 2048

__device__ __forceinline__ float iou_box(float px, float py, float pw, float ph,
                                         float glx, float guy, float grx, float gdy,
                                         float g_area) {
    float plx = fmaxf(0.0f, px - pw * 0.5f);
    float puy = fmaxf(0.0f, py - ph * 0.5f);
    float prx = fminf(IMG - 1.0f, px + pw * 0.5f);
    float pdy = fminf(IMG - 1.0f, py + ph * 0.5f);
    float p_area = (prx - plx) * (pdy - puy);
    float cl = fmaxf(plx, glx);
    float cr = fminf(prx, grx);
    float cu = fmaxf(puy, guy);
    float cd = fminf(pdy, gdy);
    float inter = (cr - cl + 1.0f) * (cd - cu + 1.0f);
    float denom = p_area + g_area - inter;
    float iou = inter / denom;
    return ((cr < cl) || (cd < cu)) ? 0.0f : iou;
}

__device__ __forceinline__ float cell_loss(float4 b0, float4 b1, float4 b2,
                                           float4 g0, float4 g1, float4 g2,
                                           int ij) {
    float gx = (float)(ij / 7) * GRID_F;
    float gy = (float)(ij % 7) * GRID_F;

    float glx = g1.y, guy = g1.z, grx = g1.w, gdy = g2.x;
    float g_area = (grx - glx) * (gdy - guy);

    float px0 = truncf(gx + b0.x * GRID_F);
    float py0 = truncf(gy + b0.y * GRID_F);
    float pw0 = truncf(b0.z * IMG);
    float ph0 = truncf(b0.w * IMG);
    float iou0 = iou_box(px0, py0, pw0, ph0, glx, guy, grx, gdy, g_area);

    float px1 = truncf(gx + b1.y * GRID_F);
    float py1 = truncf(gy + b1.z * GRID_F);
    float pw1 = truncf(b1.w * IMG);
    float ph1 = truncf(b2.x * IMG);
    float iou1 = iou_box(px1, py1, pw1, ph1, glx, guy, grx, gdy, g_area);

    int idx = (iou1 > iou0) ? 1 : 0;       // first-max tie-break (jnp.argmax)
    float max_iou = fmaxf(iou0, iou1);

    float exist = g2.y;
    float m = ((exist != 0.0f) && (max_iou > 0.0f)) ? 1.0f : 0.0f;

    float pmx = idx ? b1.y : b0.x;
    float pmy = idx ? b1.z : b0.y;
    float pmw = idx ? b1.w : b0.z;
    float pmh = idx ? b2.x : b0.w;
    float pmc = idx ? b2.y : b1.x;

    float dx = g0.x - pmx;
    float dy = g0.y - pmy;
    float dw = sqrtf(g0.z) - sqrtf(pmw);
    float dh = sqrtf(g0.w) - sqrtf(pmh);
    float coord = L_COORD * (dx * dx + dy * dy + dw * dw + dh * dh);

    float dconf = g1.x - pmc;
    float conf_obj = dconf * dconf;

    float dc0 = g2.z - b2.z;
    float dc1 = g2.w - b2.w;
    float cls = L_NOOBJ * (dc0 * dc0 + dc1 * dc1);

    float conf_noobj = L_NOOBJ * (b1.x * b1.x + b2.y * b2.y - m * pmc * pmc);

    return m * (coord + conf_obj + cls) + conf_noobj;
}

// Main kernel: grid-stride, no LDS staging, no barriers in the hot loop,
// NO global atomics — per-block partial sums to d_ws.
__global__ __launch_bounds__(256) void yolo_main(
    const float* __restrict__ bb, const float* __restrict__ gt,
    float* __restrict__ partial, int ncell) {
    const float4* __restrict__ bb4 = reinterpret_cast<const float4*>(bb);
    const float4* __restrict__ gt4 = reinterpret_cast<const float4*>(gt);

    int nthreads = gridDim.x * blockDim.x;
    int tid = blockIdx.x * blockDim.x + threadIdx.x;

    float val = 0.0f;
    for (int cell = tid; cell < ncell; cell += nthreads) {
        size_t base = (size_t)cell * 3;
        float4 b0 = bb4[base + 0];
        float4 b1 = bb4[base + 1];
        float4 b2 = bb4[base + 2];
        float4 g0 = gt4[base + 0];
        float4 g1 = gt4[base + 1];
        float4 g2 = gt4[base + 2];
        val += cell_loss(b0, b1, b2, g0, g1, g2, cell % 49);
    }

    // wave64 reduce
    #pragma unroll
    for (int off = 32; off > 0; off >>= 1)
        val += __shfl_down(val, off, 64);

    __shared__ float warp_sums[4];
    int lane = threadIdx.x & 63;
    int wid = threadIdx.x >> 6;
    if (lane == 0) warp_sums[wid] = val;
    __syncthreads();
    if (threadIdx.x == 0)
        partial[blockIdx.x] = warp_sums[0] + warp_sums[1] + warp_sums[2] + warp_sums[3];
}

// Final reduction: one block sums the 2048 partials and writes d_out.
__global__ __launch_bounds__(256) void yolo_reduce(
    const float* __restrict__ partial, float* __restrict__ out, int n) {
    float v = 0.0f;
    for (int i = threadIdx.x; i < n; i += 256)
        v += partial[i];
    #pragma unroll
    for (int off = 32; off > 0; off >>= 1)
        v += __shfl_down(v, off, 64);
    __shared__ float warp_sums[4];
    int lane = threadIdx.x & 63;
    int wid = threadIdx.x >> 6;
    if (lane == 0) warp_sums[wid] = v;
    __syncthreads();
    if (threadIdx.x == 0)
        out[0] = warp_sums[0] + warp_sums[1] + warp_sums[2] + warp_sums[3];
}

extern "C" void kernel_launch(void* const* d_in, const int* in_sizes, int n_in,
                              void* d_out, int out_size, void* d_ws, size_t ws_size,
                              hipStream_t stream) {
    const float* bb = (const float*)d_in[0];
    const float* gt = (const float*)d_in[1];
    float* out = (float*)d_out;
    float* partial = (float*)d_ws;
    int ncell = in_sizes[0] / 12;  // N*S*S = 1,605,632

    yolo_main<<<NBLOCKS, 256, 0, stream>>>(bb, gt, partial, ncell);
    yolo_reduce<<<1, 256, 0, stream>>>(partial, out, NBLOCKS);
}

// Round 10
// 169.777 us; speedup vs baseline: 1.0234x; 1.0138x over previous
//
#include <hip/hip_runtime.h>

#define IMG 448.0f
#define GRID_F 64.0f
#define L_COORD 5.0f
#define L_NOOBJ 0.5f
#define NBLK 1568
#define TPB 256
#define UNROLL 4
// NBLK*TPB*UNROLL = 1,605,632 == ncell exactly -> guard-free fast path.
// nthreads = NBLK*TPB = 401,408 = 49 * 8192 -> cell % 49 invariant across k.

__device__ __forceinline__ float iou_box(float px, float py, float pw, float ph,
                                         float glx, float guy, float grx, float gdy,
                                         float g_area) {
    float plx = fmaxf(0.0f, px - pw * 0.5f);
    float puy = fmaxf(0.0f, py - ph * 0.5f);
    float prx = fminf(IMG - 1.0f, px + pw * 0.5f);
    float pdy = fminf(IMG - 1.0f, py + ph * 0.5f);
    float p_area = (prx - plx) * (pdy - puy);
    float cl = fmaxf(plx, glx);
    float cr = fminf(prx, grx);
    float cu = fmaxf(puy, guy);
    float cd = fminf(pdy, gdy);
    float inter = (cr - cl + 1.0f) * (cd - cu + 1.0f);
    float denom = p_area + g_area - inter;
    float iou = inter / denom;
    return ((cr < cl) || (cd < cu)) ? 0.0f : iou;
}

__device__ __forceinline__ float cell_loss(float4 b0, float4 b1, float4 b2,
                                           float4 g0, float4 g1, float4 g2,
                                           float gx, float gy) {
    float glx = g1.y, guy = g1.z, grx = g1.w, gdy = g2.x;
    float g_area = (grx - glx) * (gdy - guy);

    float px0 = truncf(gx + b0.x * GRID_F);
    float py0 = truncf(gy + b0.y * GRID_F);
    float pw0 = truncf(b0.z * IMG);
    float ph0 = truncf(b0.w * IMG);
    float iou0 = iou_box(px0, py0, pw0, ph0, glx, guy, grx, gdy, g_area);

    float px1 = truncf(gx + b1.y * GRID_F);
    float py1 = truncf(gy + b1.z * GRID_F);
    float pw1 = truncf(b1.w * IMG);
    float ph1 = truncf(b2.x * IMG);
    float iou1 = iou_box(px1, py1, pw1, ph1, glx, guy, grx, gdy, g_area);

    int idx = (iou1 > iou0) ? 1 : 0;       // first-max tie-break (jnp.argmax)
    float max_iou = fmaxf(iou0, iou1);

    float exist = g2.y;
    float m = ((exist != 0.0f) && (max_iou > 0.0f)) ? 1.0f : 0.0f;

    float pmx = idx ? b1.y : b0.x;
    float pmy = idx ? b1.z : b0.y;
    float pmw = idx ? b1.w : b0.z;
    float pmh = idx ? b2.x : b0.w;
    float pmc = idx ? b2.y : b1.x;

    float dx = g0.x - pmx;
    float dy = g0.y - pmy;
    float dw = sqrtf(g0.z) - sqrtf(pmw);
    float dh = sqrtf(g0.w) - sqrtf(pmh);
    float coord = L_COORD * (dx * dx + dy * dy + dw * dw + dh * dh);

    float dconf = g1.x - pmc;
    float conf_obj = dconf * dconf;

    float dc0 = g2.z - b2.z;
    float dc1 = g2.w - b2.w;
    float cls = L_NOOBJ * (dc0 * dc0 + dc1 * dc1);

    float conf_noobj = L_NOOBJ * (b1.x * b1.x + b2.y * b2.y - m * pmc * pmc);

    return m * (coord + conf_obj + cls) + conf_noobj;
}

__global__ __launch_bounds__(256) void yolo_main(
    const float* __restrict__ bb, const float* __restrict__ gt,
    float* __restrict__ partial, int ncell) {
    const float4* __restrict__ bb4 = reinterpret_cast<const float4*>(bb);
    const float4* __restrict__ gt4 = reinterpret_cast<const float4*>(gt);

    int nthreads = gridDim.x * blockDim.x;
    int tid = blockIdx.x * blockDim.x + threadIdx.x;
    float val = 0.0f;

    if (ncell == UNROLL * nthreads && (nthreads % 49) == 0) {
        // Guard-free: 24 loads issued back-to-back, no exec-mask splits.
        const size_t STEP = (size_t)3 * nthreads;  // float4 step between batches
        const float4* bp = bb4 + (size_t)tid * 3;
        const float4* gp = gt4 + (size_t)tid * 3;

        float4 B00 = bp[0],          B01 = bp[1],          B02 = bp[2];
        float4 B10 = bp[STEP + 0],   B11 = bp[STEP + 1],   B12 = bp[STEP + 2];
        float4 B20 = bp[2*STEP + 0], B21 = bp[2*STEP + 1], B22 = bp[2*STEP + 2];
        float4 B30 = bp[3*STEP + 0], B31 = bp[3*STEP + 1], B32 = bp[3*STEP + 2];
        float4 G00 = gp[0],          G01 = gp[1],          G02 = gp[2];
        float4 G10 = gp[STEP + 0],   G11 = gp[STEP + 1],   G12 = gp[STEP + 2];
        float4 G20 = gp[2*STEP + 0], G21 = gp[2*STEP + 1], G22 = gp[2*STEP + 2];
        float4 G30 = gp[3*STEP + 0], G31 = gp[3*STEP + 1], G32 = gp[3*STEP + 2];

        int ij = tid % 49;                  // invariant across the 4 cells
        float gx = (float)(ij / 7) * GRID_F;
        float gy = (float)(ij % 7) * GRID_F;

        val += cell_loss(B00, B01, B02, G00, G01, G02, gx, gy);
        val += cell_loss(B10, B11, B12, G10, G11, G12, gx, gy);
        val += cell_loss(B20, B21, B22, G20, G21, G22, gx, gy);
        val += cell_loss(B30, B31, B32, G30, G31, G32, gx, gy);
    } else {
        // Fallback (never taken for this problem size, kept for safety).
        for (int cell = tid; cell < ncell; cell += nthreads) {
            size_t base = (size_t)cell * 3;
            int ij = cell % 49;
            val += cell_loss(bb4[base], bb4[base + 1], bb4[base + 2],
                             gt4[base], gt4[base + 1], gt4[base + 2],
                             (float)(ij / 7) * GRID_F, (float)(ij % 7) * GRID_F);
        }
    }

    // wave64 reduce
    #pragma unroll
    for (int off = 32; off > 0; off >>= 1)
        val += __shfl_down(val, off, 64);

    __shared__ float warp_sums[4];
    int lane = threadIdx.x & 63;
    int wid = threadIdx.x >> 6;
    if (lane == 0) warp_sums[wid] = val;
    __syncthreads();
    if (threadIdx.x == 0)
        partial[blockIdx.x] = warp_sums[0] + warp_sums[1] + warp_sums[2] + warp_sums[3];
}

__global__ __launch_bounds__(256) void yolo_reduce(
    const float* __restrict__ partial, float* __restrict__ out, int n) {
    float v = 0.0f;
    for (int i = threadIdx.x; i < n; i += 256)
        v += partial[i];
    #pragma unroll
    for (int off = 32; off > 0; off >>= 1)
        v += __shfl_down(v, off, 64);
    __shared__ float warp_sums[4];
    int lane = threadIdx.x & 63;
    int wid = threadIdx.x >> 6;
    if (lane == 0) warp_sums[wid] = v;
    __syncthreads();
    if (threadIdx.x == 0)
        out[0] = warp_sums[0] + warp_sums[1] + warp_sums[2] + warp_sums[3];
}

extern "C" void kernel_launch(void* const* d_in, const int* in_sizes, int n_in,
                              void* d_out, int out_size, void* d_ws, size_t ws_size,
                              hipStream_t stream) {
    const float* bb = (const float*)d_in[0];
    const float* gt = (const float*)d_in[1];
    float* out = (float*)d_out;
    float* partial = (float*)d_ws;
    int ncell = in_sizes[0] / 12;  // N*S*S = 1,605,632

    yolo_main<<<NBLK, TPB, 0, stream>>>(bb, gt, partial, ncell);
    yolo_reduce<<<1, 256, 0, stream>>>(partial, out, NBLK);
}